// Round 8
// baseline (338.738 us; speedup 1.0000x reference)
//
#include <hip/hip_runtime.h>

typedef _Float16 half8 __attribute__((ext_vector_type(8)));
typedef float floatx4 __attribute__((ext_vector_type(4)));

__device__ __forceinline__ float rcpf_(float x) { return __builtin_amdgcn_rcpf(x); }
__device__ __forceinline__ float exp2f_(float x) { return __builtin_amdgcn_exp2f(x); }

// Barrier that does NOT drain vmem: only LDS ops published.
// 0xC07F = vmcnt(63) expcnt(7) lgkmcnt(0).
template<bool MULTI_WAVE>
__device__ __forceinline__ void lds_publish_barrier() {
    asm volatile("" ::: "memory");
    __builtin_amdgcn_s_waitcnt(0xC07F);
    if constexpr (MULTI_WAVE) __builtin_amdgcn_s_barrier();
    asm volatile("" ::: "memory");
}

struct AllParams {
    const float *x;
    const float *w1f_k, *w1f_b, *w1b_k, *w1b_b;
    const float *w2f_k, *w2f_b, *w2b_k, *w2b_b;
    const float *w3f_k, *w3f_b, *w3b_k, *w3b_b;
    const float *w1f_r, *w1b_r, *w2f_r, *w2b_r, *w3f_r, *w3b_r;
    const float *d3_w, *d3_b, *cls_w, *cls_b;
    _Float16 *x16, *h1, *h2;
    float *h3;
    half8 *wf; float4 *bf4;
    unsigned *flags;                   // [3][128] pair flags, zeroed by prep
    float *out;
};

// ---------- pack Wk weights + bias into per-(dir,wave,lane) MFMA B-fragments.
// exp2-folding: gates i,f,o scaled by log2e; gate g (tanh) by 2*log2e.
template<int F_REAL, int XT, int U>
__device__ __forceinline__ void pack_one(int dir, int wave, int lane,
    const float* Wk_f, const float* b_f, const float* Wk_b, const float* b_b,
    half8* wf, float4* bf4)
{
    constexpr int N  = 4 * U;
    constexpr int NW = U / 16;
    const int quad = lane >> 4, l16 = lane & 15;
    const float* Wk = dir ? Wk_b : Wk_f;
    const float* bs = dir ? b_b  : b_f;
    const int ucol = wave * 16 + l16;
    const long base = ((long)(dir * NW + wave) * 64 + lane) * (4 * XT);
    #pragma unroll
    for (int g = 0; g < 4; g++) {
        const float sc = (g == 2) ? 2.88539008177793f : 1.44269504088896f;
        const int n = g * U + ucol;
        #pragma unroll
        for (int kt = 0; kt < XT; kt++) {
            half8 h;
            #pragma unroll
            for (int j = 0; j < 8; j++) {
                const int k = kt * 32 + quad * 8 + j;
                h[j] = (k < F_REAL) ? (_Float16)(Wk[k * N + n] * sc) : (_Float16)0;
            }
            wf[base + g * XT + kt] = h;
        }
    }
    float4 b;
    b.x = bs[0 * U + ucol] * 1.44269504088896f;
    b.y = bs[1 * U + ucol] * 1.44269504088896f;
    b.z = bs[2 * U + ucol] * 2.88539008177793f;
    b.w = bs[3 * U + ucol] * 1.44269504088896f;
    bf4[(dir * NW + wave) * 64 + lane] = b;
}

// ---------- prep: pack all layers + coalesced x->f16 + flag reset.
__global__ __launch_bounds__(256)
void prep(AllParams p)
{
    const int gid = blockIdx.x * 256 + threadIdx.x;    // 1572864 threads
    if (gid < 512) {
        pack_one<78, 3, 64>(gid >> 8, (gid >> 6) & 3, gid & 63,
                            p.w1f_k, p.w1f_b, p.w1b_k, p.w1b_b, p.wf, p.bf4);
    } else if (gid < 768) {
        const int t2 = gid - 512;
        pack_one<128, 4, 32>(t2 >> 7, (t2 >> 6) & 1, t2 & 63,
                             p.w2f_k, p.w2f_b, p.w2b_k, p.w2b_b, p.wf + 6144, p.bf4 + 512);
    } else if (gid < 896) {
        const int t3 = gid - 768;
        pack_one<64, 2, 16>(t3 >> 6, 0, t3 & 63,
                            p.w3f_k, p.w3f_b, p.w3b_k, p.w3b_b, p.wf + 10240, p.bf4 + 768);
    }
    if (gid >= 1024 && gid < 1024 + 384) p.flags[gid - 1024] = 0u;  // replay-safe

    // x -> f16: element block e = gid*8 (col never crosses a 96-row: 8 | 96)
    const int e   = gid * 8;                           // < 12582912
    const int r   = e / 96;
    const int col = e - r * 96;
    half8 h = {};
    if (col < 78) {
        const float* ip = p.x + (long)r * 78 + col;
        const int n = (col == 72) ? 6 : 8;             // cols 78,79 -> pad 0
        #pragma unroll
        for (int j = 0; j < 8; j += 2) {
            if (j < n) {
                const float2 v = *(const float2*)(ip + j);
                h[j] = (_Float16)v.x; h[j + 1] = (_Float16)v.y;
            }
        }
    }
    *(half8*)(p.x16 + e) = h;
}

// ---------- pair flag sync: block's partner (other dir, same bg) must finish
// the phase before this block reads pair-produced data. Fence/atomic protocol
// identical to R3's verified grid_barrier, scoped to a 2-block pair.
// Executed UNCONDITIONALLY by all 256 threads (uniform convergent path).
__device__ __forceinline__ void phase_sync(unsigned* flag)
{
    __syncthreads();                   // all waves done; drains vm+lgkm
    if (threadIdx.x == 0) {
        __threadfence();               // publish this block's stores device-wide
        atomicAdd(flag, 1u);
        while (__hip_atomic_load(flag, __ATOMIC_ACQUIRE, __HIP_MEMORY_SCOPE_AGENT) < 2u)
            __builtin_amdgcn_s_sleep(2);
        __threadfence();               // invalidate stale caches before reads
    }
    __syncthreads();
}

// ---------- fused recurrence phase (R=8, proven config): z = in@Wk pre-barrier,
// += h@Wr post-barrier, exp2 gates, bias as MFMA C-init, PF-deep prefetch.
// A rows 8..15 duplicate rows 0..7 (ds_read broadcast) -> NO shuffles.
// wr: this thread owns its outputs. Duplicate (non-wr) waves compute the same
// values from the same inputs but store nothing -- they exist so that every
// s_barrier inside is executed by ALL waves of the block on a UNIFORM path
// (convergent-op rule; thread-divergent barriers are UB -> R7 hang).
template<int U, int XT, int HT, bool SEQ_OUT, int IN_F, int PF, bool MW>
__device__ __forceinline__ void rec_phase(
    const int tl, const int dir, const int bg, const bool wr,
    const _Float16* __restrict__ in,
    const half8* __restrict__ wf, const float4* __restrict__ bf4,
    const float* __restrict__ Wr,
    _Float16* __restrict__ hseq, float* __restrict__ hlast,
    _Float16* __restrict__ H)          // flat [2][8][HROW] f16 region
{
    constexpr int T    = 128;
    constexpr int N    = 4 * U;
    constexpr int NW   = U / 16;
    constexpr int HROW = HT * 32 + 8;
    constexpr int THREADS = NW * 64;
    static_assert(T % PF == 0, "PF must divide T");

    const int wave = tl >> 6;
    const int lane = tl & 63;
    const int quad = lane >> 4;
    const int l16  = lane & 15;
    const int bbase = bg * 8;
    const int ucol  = wave * 16 + l16;

    if (wr) {
        for (int i = tl; i < 2 * 8 * HROW; i += THREADS)
            H[i] = (_Float16)0;        // h0=0; pad and k>=U stay 0
    }

    const long wbase = ((long)(dir * NW + wave) * 64 + lane) * (4 * XT);
    half8 wk[4][XT];
    #pragma unroll
    for (int g = 0; g < 4; g++)
        #pragma unroll
        for (int kt = 0; kt < XT; kt++)
            wk[g][kt] = wf[wbase + g * XT + kt];
    const float4 b4 = bf4[(dir * NW + wave) * 64 + lane];
    floatx4 biasv[4];
    {
        const float bb[4] = {b4.x, b4.y, b4.z, b4.w};
        #pragma unroll
        for (int g = 0; g < 4; g++) {
            floatx4 v = {bb[g], bb[g], bb[g], bb[g]};
            biasv[g] = v;
        }
    }

    half8 br[4][HT];
    #pragma unroll
    for (int g = 0; g < 4; g++) {
        const float sc = (g == 2) ? 2.88539008177793f : 1.44269504088896f;
        const int n = g * U + ucol;
        #pragma unroll
        for (int ht = 0; ht < HT; ht++) {
            half8 h;
            #pragma unroll
            for (int j = 0; j < 8; j++) {
                const int k = ht * 32 + quad * 8 + j;
                h[j] = (k < U) ? (_Float16)(Wr[k * N + n] * sc) : (_Float16)0;
            }
            br[g][ht] = h;
        }
    }

    // running per-lane input pointer (<=PF-row overshoot lands in ws slack)
    const int arow = bbase + (l16 & 7);
    const _Float16* xp = in + (long)arow * T * IN_F + quad * 8
                       + (dir ? (long)(T - 1) * IN_F : 0);
    const long xd = dir ? -(long)IN_F : (long)IN_F;
    auto load_x = [&](half8* xr) {
        #pragma unroll
        for (int kt = 0; kt < XT; kt++)
            xr[kt] = *(const half8*)(xp + kt * 32);
        xp += xd;
    };

    // quad -> 2 chains: q0:{0,1} q1:{4,5} q2:{2,3} q3:{6,7}
    const int rowbase = (quad & 1) * 4 + (quad >> 1) * 2;
    const bool hi_rows = (quad & 2) != 0;
    float c_reg[2] = {0.0f, 0.0f};

    const int tp0 = dir ? (T - 1) : 0;
    const long hs_stride = (long)T * (2 * U);
    _Float16* hs_ptr = SEQ_OUT
        ? hseq + ((long)(bbase + rowbase) * T + tp0) * (2 * U) + dir * U + ucol
        : nullptr;
    const long hs_delta = dir ? -(long)(2 * U) : (long)(2 * U);

    auto step = [&](int t, half8* xr) {
        // z-part: independent of H -> issued before barrier, latency hidden
        floatx4 acc[4];
        #pragma unroll
        for (int g = 0; g < 4; g++)
            acc[g] = __builtin_amdgcn_mfma_f32_16x16x32_f16(xr[0], wk[g][0], biasv[g], 0, 0, 0);
        #pragma unroll
        for (int kt = 1; kt < XT; kt++)
            #pragma unroll
            for (int g = 0; g < 4; g++)
                acc[g] = __builtin_amdgcn_mfma_f32_16x16x32_f16(xr[kt], wk[g][kt], acc[g], 0, 0, 0);
        load_x(xr);                    // refill slot (reads t+PF); stays in flight
        lds_publish_barrier<MW>();
        const _Float16* hb = H + (((t & 1) * 8 + (l16 & 7)) * HROW);  // dup rows
        #pragma unroll
        for (int ht = 0; ht < HT; ht++) {
            const half8 ha = *(const half8*)(hb + ht * 32 + quad * 8);
            #pragma unroll
            for (int g = 0; g < 4; g++)
                acc[g] = __builtin_amdgcn_mfma_f32_16x16x32_f16(ha, br[g][ht], acc[g], 0, 0, 0);
        }
        float hq[2];
        #pragma unroll
        for (int s = 0; s < 2; s++) {
            const int r = hi_rows ? (2 + s) : s;
            const float ig = rcpf_(1.0f + exp2f_(-acc[0][r]));
            const float fg = rcpf_(1.0f + exp2f_(-acc[1][r]));
            const float gg = 1.0f - 2.0f * rcpf_(exp2f_(acc[2][r]) + 1.0f);
            const float og = rcpf_(1.0f + exp2f_(-acc[3][r]));
            const float c  = fg * c_reg[s] + ig * gg;
            c_reg[s] = c;
            const float th = 1.0f - 2.0f * rcpf_(exp2f_(c * 2.88539008177793f) + 1.0f);
            hq[s] = og * th;
        }
        if (wr) {
            #pragma unroll
            for (int s = 0; s < 2; s++)
                H[(((t + 1) & 1) * 8 + rowbase + s) * HROW + ucol] = (_Float16)hq[s];
        }
        if constexpr (SEQ_OUT) {
            if (wr) {
                #pragma unroll
                for (int s = 0; s < 2; s++)
                    hs_ptr[s * hs_stride] = (_Float16)hq[s];
            }
            hs_ptr += hs_delta;
        } else {
            if (t == T - 1 && wr) {
                #pragma unroll
                for (int s = 0; s < 2; s++)
                    hlast[(bbase + rowbase + s) * (2 * U) + dir * U + ucol] = hq[s];
            }
        }
    };

    // PF-deep prologue prefetch (rotating register buffers, static indices)
    half8 xq[PF][XT];
    #pragma unroll
    for (int i = 0; i < PF; i++) load_x(xq[i]);
    lds_publish_barrier<MW>();         // H zero-init visible (barrier #1)

    for (int tt = 0; tt < T; tt += PF) {
        #pragma unroll
        for (int i = 0; i < PF; i++)
            step(tt + i, xq[i]);
    }
}

// ---------- mono: L1 -> L2 -> L3 -> dense, one block = one (dir,bg) stream
// through all layers. Pair flags instead of grid barriers: block only waits
// for its partner (1-dir, bg), which is co-resident and on the SAME XCD
// (partner = bid +- 128, 128 % 8 == 0), so h1/h2/h3 exchange is L2-local.
// Barrier-uniformity: L1, L2 run all 256 threads (L2 waves 2-3 as non-writing
// duplicates); L3's instantiation has no barriers (MW=false), so its tid<64
// guard is legal; phase_sync is unconditional.
__global__ __launch_bounds__(256)
void mono(AllParams p)
{
    __shared__ __align__(16) _Float16 HS[2 * 8 * 72];  // max phase (L1 HROW=72)
    const int tid = threadIdx.x, bid = blockIdx.x;
    const int dir = bid >> 7, bg = bid & 127;

    // L1: all 4 waves, all writers
    rec_phase<64, 3, 2, true, 96, 4, true>(tid, dir, bg, true, p.x16, p.wf, p.bf4,
        dir ? p.w1b_r : p.w1f_r, p.h1, nullptr, HS);
    phase_sync(p.flags + bg);

    // L2: all 4 waves on a uniform path; waves 2-3 duplicate waves 0-1
    // (tl = tid & 127) and store nothing -> barrier counts match by construction.
    rec_phase<32, 4, 1, true, 128, 4, true>(tid & 127, dir, bg, tid < 128,
        p.h1, p.wf + 6144, p.bf4 + 512,
        dir ? p.w2b_r : p.w2f_r, p.h2, nullptr, HS);
    phase_sync(p.flags + 128 + bg);

    // L3: wave 0 only -- this instantiation contains ZERO barriers (MW=false)
    if (tid < 64) {
        rec_phase<16, 2, 1, false, 64, 8, false>(tid, dir, bg, true,
            p.h2, p.wf + 10240, p.bf4 + 768,
            dir ? p.w3b_r : p.w3f_r, nullptr, p.h3, HS);
    }
    phase_sync(p.flags + 256 + bg);

    // dense head: pair covers 8 rows; this block does 4 (dir-split)
    if (tid < 12) {
        const int r = bg * 8 + dir * 4 + tid / 3;
        const int c = tid - (tid / 3) * 3;
        const float* hr = p.h3 + r * 32;
        float s = p.cls_b[c];
        #pragma unroll
        for (int j = 0; j < 8; j++) {
            float a = p.d3_b[j];
            #pragma unroll
            for (int k = 0; k < 32; k++) a += hr[k] * p.d3_w[k * 8 + j];
            s += fmaxf(a, 0.0f) * p.cls_w[j * 3 + c];
        }
        p.out[r * 3 + c] = 1.0f / (1.0f + __expf(-s));
    }
}

extern "C" void kernel_launch(void* const* d_in, const int* in_sizes, int n_in,
                              void* d_out, int out_size, void* d_ws, size_t ws_size,
                              hipStream_t stream)
{
    char* ws = (char*)d_ws;
    AllParams p;
    p.x     = (const float*)d_in[0];
    p.w1f_k = (const float*)d_in[1];  p.w1f_r = (const float*)d_in[2];  p.w1f_b = (const float*)d_in[3];
    p.w1b_k = (const float*)d_in[4];  p.w1b_r = (const float*)d_in[5];  p.w1b_b = (const float*)d_in[6];
    p.w2f_k = (const float*)d_in[7];  p.w2f_r = (const float*)d_in[8];  p.w2f_b = (const float*)d_in[9];
    p.w2b_k = (const float*)d_in[10]; p.w2b_r = (const float*)d_in[11]; p.w2b_b = (const float*)d_in[12];
    p.w3f_k = (const float*)d_in[13]; p.w3f_r = (const float*)d_in[14]; p.w3f_b = (const float*)d_in[15];
    p.w3b_k = (const float*)d_in[16]; p.w3b_r = (const float*)d_in[17]; p.w3b_b = (const float*)d_in[18];
    p.d3_w  = (const float*)d_in[19]; p.d3_b  = (const float*)d_in[20];
    p.cls_w = (const float*)d_in[21]; p.cls_b = (const float*)d_in[22];

    // workspace (4KB headroom before x16 for bwd-dir prefetch overshoot;
    // inter-buffer slack absorbs fwd overshoot of each phase)
    p.x16   = (_Float16*)(ws + 4096);          // 25.2 MB [131072][96]
    p.h1    = (_Float16*)(ws + 33554432);      // 33.5 MB [1024][128][128]
    p.h2    = (_Float16*)(ws + 67108864);      // 16.8 MB [1024][128][64]
    p.h3    = (float*)   (ws + 83886080);      // 131 KB  [1024][32]
    p.wf    = (half8*)   (ws + 84017152);      // 176 KB packed Wk frags
    p.bf4   = (float4*)  (ws + 84197376);      // 14 KB scaled biases
    p.flags = (unsigned*)(ws + 84211712);      // 3*128 pair flags
    p.out   = (float*)d_out;

    prep<<<dim3(6144), dim3(256), 0, stream>>>(p);
    mono<<<dim3(256),  dim3(256), 0, stream>>>(p);
}